// Round 12
// baseline (159.019 us; speedup 1.0000x reference)
//
#include <hip/hip_runtime.h>

// GCN forward: out = PReLU( D^-1/2 (A+I) D^-1/2 (x@W) + b )
// Aggregation commutes with the linear map:
//   xs[i,:] = bf16( dinv[i] * x[i,:] ),  dinv[i] = rsqrt(deg[i]+1)
//   xa[i,:] = bf16( dinv[i] * ( xs[i,:] + sum_{s->i} xs[s,:] ) )
//   out     = PReLU( xa @ W + b )
// R12 = R11 + (a) k5 processes 2 independent nodes per wave (interleaved
//              chains, 2x memory-level parallelism per wave), nt xa stores;
//          (b) k6 direct nontemporal epilogue (no LDS transpose, fewer
//              barriers — R4 measured LDS-vs-direct neutral).

typedef __attribute__((ext_vector_type(8))) short bf16x8_t;
typedef __attribute__((ext_vector_type(4))) float f32x4;

#define N_NODES 100000
#define N_EDGES 500000
#define K_IN    128
#define H_OUT   512
#define MAXDEG  32
#define NEB     1954     // ceil(N_EDGES/256)

static __device__ __forceinline__ unsigned short f2b(float f) {
    unsigned u = __float_as_uint(f);
    u = (u + 0x7FFFu + ((u >> 16) & 1u)) >> 16;   // RNE
    return (unsigned short)u;
}
static __device__ __forceinline__ float b2lo(unsigned v) {
    return __uint_as_float(v << 16);
}
static __device__ __forceinline__ float b2hi(unsigned v) {
    return __uint_as_float(v & 0xFFFF0000u);
}

// K1: deg histogram + INLINE padded-CSR fill (atomic old value = slot) | prepW
__global__ __launch_bounds__(256) void k1(const int* __restrict__ ei,
                                          int* __restrict__ deg,
                                          int* __restrict__ csrp,
                                          const float* __restrict__ W,
                                          unsigned short* __restrict__ Wt) {
    int b = blockIdx.x;
    if (b < NEB) {
        int e = b * 256 + threadIdx.x;
        if (e < N_EDGES) {
            int s = ei[e];
            int d = ei[N_EDGES + e];
            int r = atomicAdd(&deg[d], 1);
            csrp[d * MAXDEG + r] = s;
        }
    } else {
        int i = (b - NEB) * 256 + threadIdx.x;   // i = n*128+k
        int n = i >> 7, k = i & 127;
        Wt[i] = f2b(W[k * H_OUT + n]);
    }
}

// K2: xs[i] = bf16( rsqrt(deg+1) * x[i] ) — pure streaming.
__global__ __launch_bounds__(256) void k2(const int* __restrict__ deg,
                                          const float* __restrict__ x,
                                          unsigned* __restrict__ xs) {
    int i = blockIdx.x * 256 + threadIdx.x;      // 0 .. 6.4M-1
    int row = i >> 6;
    float d = rsqrtf((float)(deg[row] + 1));     // broadcast across wave
    const float2* x2 = (const float2*)x;
    float2 xv = x2[i];
    xs[i] = ((unsigned)f2b(d * xv.y) << 16) | f2b(d * xv.x);
}

// K5: xa[i] = bf16( dinv[i] * (xs[i] + sum_{s->i} xs[s]) ).
// TWO nodes per wave (2b, 2b+1), chains interleaved: adjacency int4 loads
// and all 16 gathers issued unconditionally (clamped idx), value-masked
// accumulate. Nontemporal xa stores (don't evict xs from L2).
__global__ __launch_bounds__(256) void k5(const unsigned* __restrict__ xs,
                                          const int* __restrict__ csrp,
                                          const int* __restrict__ deg,
                                          unsigned* __restrict__ xa) {
    int wave = threadIdx.x >> 6, lane = threadIdx.x & 63;
    int n0 = blockIdx.x * 8 + wave * 2;          // grid exactly covers pairs
    int n1 = n0 + 1;

    unsigned sv0 = xs[(size_t)n0 * 64 + lane];
    unsigned sv1 = xs[(size_t)n1 * 64 + lane];
    int cnt0 = __builtin_amdgcn_readfirstlane(deg[n0]);
    int cnt1 = __builtin_amdgcn_readfirstlane(deg[n1]);
    float a00 = b2lo(sv0), a01 = b2hi(sv0);
    float a10 = b2lo(sv1), a11 = b2hi(sv1);

    const int4* cp0 = (const int4*)(csrp + n0 * MAXDEG);
    const int4* cp1 = (const int4*)(csrp + n1 * MAXDEG);
    int cmax = cnt0 > cnt1 ? cnt0 : cnt1;

    for (int j = 0; j < cmax; j += 8) {
        int4 ca0 = cp0[(j >> 2)];
        int4 cb0 = cp0[(j >> 2) + 1];
        int4 ca1 = cp1[(j >> 2)];
        int4 cb1 = cp1[(j >> 2) + 1];
        unsigned i0[8] = {(unsigned)ca0.x, (unsigned)ca0.y, (unsigned)ca0.z, (unsigned)ca0.w,
                          (unsigned)cb0.x, (unsigned)cb0.y, (unsigned)cb0.z, (unsigned)cb0.w};
        unsigned i1[8] = {(unsigned)ca1.x, (unsigned)ca1.y, (unsigned)ca1.z, (unsigned)ca1.w,
                          (unsigned)cb1.x, (unsigned)cb1.y, (unsigned)cb1.z, (unsigned)cb1.w};
        unsigned v0[8], v1[8];
        #pragma unroll
        for (int t = 0; t < 8; ++t) {
            unsigned id0 = i0[t] < N_NODES ? i0[t] : 0u;   // clamp poison
            unsigned id1 = i1[t] < N_NODES ? i1[t] : 0u;
            v0[t] = xs[(size_t)id0 * 64 + lane];
            v1[t] = xs[(size_t)id1 * 64 + lane];
        }
        int rem0 = cnt0 - j, rem1 = cnt1 - j;   // wave-uniform
        #pragma unroll
        for (int t = 0; t < 8; ++t) {
            unsigned w0 = (t < rem0) ? v0[t] : 0u;
            unsigned w1 = (t < rem1) ? v1[t] : 0u;
            a00 += b2lo(w0); a01 += b2hi(w0);
            a10 += b2lo(w1); a11 += b2hi(w1);
        }
    }
    float d0 = rsqrtf((float)(cnt0 + 1));
    float d1 = rsqrtf((float)(cnt1 + 1));
    unsigned p0 = ((unsigned)f2b(d0 * a01) << 16) | f2b(d0 * a00);
    unsigned p1 = ((unsigned)f2b(d1 * a11) << 16) | f2b(d1 * a10);
    __builtin_nontemporal_store(p0, &xa[(size_t)n0 * 64 + lane]);
    __builtin_nontemporal_store(p1, &xa[(size_t)n1 * 64 + lane]);
}

// K6: out = PReLU(xa @ W + b). Each block: one 128-col B tile staged once,
// TWO 128-row m-tiles against it. 4 waves (2x2), wave = 64x64 via 4x4 mfma
// 16x16x32 bf16. XOR-swizzled LDS staging; DIRECT nontemporal epilogue.
// Grid 1564 = 4 n-tiles x 391 m-pairs; bijective q/r XCD swizzle (q=195,r=4).
__global__ __launch_bounds__(256) void k6(const unsigned short* __restrict__ xa,
                                          const unsigned short* __restrict__ Wt,
                                          const float* __restrict__ bias,
                                          const float* __restrict__ pw,
                                          float* __restrict__ out) {
    __shared__ char smem[65536];
    uint4* sA = (uint4*)smem;              // 32 KB
    uint4* sB = (uint4*)(smem + 32768);    // 32 KB (persists across m-tiles)

    // bijective XCD swizzle for NWG=1564: q=195, r=4
    int orig = blockIdx.x;
    int xcd = orig & 7, loc = orig >> 3;
    int wgid = (xcd < 4 ? xcd * 196 : 784 + (xcd - 4) * 195) + loc;
    const int n0 = (wgid & 3) * 128;
    const int mpair = wgid >> 2;           // 0..390
    const int tid = threadIdx.x;

    const uint4* A4 = (const uint4*)xa;
    const uint4* B4 = (const uint4*)Wt;

    // stage B once
    #pragma unroll
    for (int r = 0; r < 8; ++r) {
        int i = tid + r * 256;
        int row = i >> 4, c = i & 15;
        sB[row * 16 + (c ^ (row & 7))] = B4[(size_t)(n0 + row) * 16 + c];
    }

    const int lane = tid & 63, wave = tid >> 6;
    const int wr = wave >> 1, wc = wave & 1;
    const int l16 = lane & 15, lq = lane >> 4;

    float bn[4], pn[4];
    #pragma unroll
    for (int n = 0; n < 4; ++n) {
        int gn = n0 + wc * 64 + n * 16 + l16;
        bn[n] = bias[gn];
        pn[n] = pw[gn];
    }

    for (int half = 0; half < 2; ++half) {
        const int m0 = (mpair * 2 + half) * 128;
        if (half) __syncthreads();   // previous half's sA reads complete

        // stage A for this m-tile
        #pragma unroll
        for (int r = 0; r < 8; ++r) {
            int i = tid + r * 256;
            int row = i >> 4, c = i & 15;
            int grow = m0 + row;
            uint4 o = (grow < N_NODES) ? A4[(size_t)grow * 16 + c]
                                       : make_uint4(0u, 0u, 0u, 0u);
            sA[row * 16 + (c ^ (row & 7))] = o;
        }
        __syncthreads();   // A (and B on first pass) visible

        f32x4 acc[4][4];
        #pragma unroll
        for (int m = 0; m < 4; ++m)
            #pragma unroll
            for (int n = 0; n < 4; ++n)
                acc[m][n] = (f32x4){0.f, 0.f, 0.f, 0.f};

        #pragma unroll
        for (int kk = 0; kk < 4; ++kk) {
            bf16x8_t av[4], bv[4];
            #pragma unroll
            for (int m = 0; m < 4; ++m) {
                int row = wr * 64 + m * 16 + l16;
                av[m] = __builtin_bit_cast(bf16x8_t, sA[row * 16 + ((kk * 4 + lq) ^ (row & 7))]);
            }
            #pragma unroll
            for (int n = 0; n < 4; ++n) {
                int row = wc * 64 + n * 16 + l16;
                bv[n] = __builtin_bit_cast(bf16x8_t, sB[row * 16 + ((kk * 4 + lq) ^ (row & 7))]);
            }
            #pragma unroll
            for (int m = 0; m < 4; ++m)
                #pragma unroll
                for (int n = 0; n < 4; ++n)
                    acc[m][n] = __builtin_amdgcn_mfma_f32_16x16x32_bf16(av[m], bv[n], acc[m][n], 0, 0, 0);
        }

        // direct epilogue: bias + PReLU, nontemporal scalar stores
        #pragma unroll
        for (int m = 0; m < 4; ++m) {
            #pragma unroll
            for (int r = 0; r < 4; ++r) {
                int gm = m0 + wr * 64 + m * 16 + lq * 4 + r;
                if (gm < N_NODES) {
                    #pragma unroll
                    for (int n = 0; n < 4; ++n) {
                        int gn = n0 + wc * 64 + n * 16 + l16;
                        float t = acc[m][n][r] + bn[n];
                        float v = t >= 0.f ? t : pn[n] * t;
                        __builtin_nontemporal_store(v, &out[(size_t)gm * H_OUT + gn]);
                    }
                }
            }
        }
    }
}

extern "C" void kernel_launch(void* const* d_in, const int* in_sizes, int n_in,
                              void* d_out, int out_size, void* d_ws, size_t ws_size,
                              hipStream_t stream) {
    const float* x    = (const float*)d_in[0];
    const int*   ei   = (const int*)d_in[1];
    const float* W    = (const float*)d_in[2];
    const float* bias = (const float*)d_in[3];
    const float* pw   = (const float*)d_in[4];
    float* out = (float*)d_out;

    char* ws = (char*)d_ws;
    size_t off = 0;
    auto alloc = [&](size_t bytes) -> void* {
        void* p = ws + off;
        off += (bytes + 255) & ~(size_t)255;
        return p;
    };
    unsigned*       xs   = (unsigned*)alloc((size_t)N_NODES * K_IN * 2);       // 25.6 MB
    unsigned*       xa   = (unsigned*)alloc((size_t)N_NODES * K_IN * 2);       // 25.6 MB
    unsigned short* Wt   = (unsigned short*)alloc((size_t)K_IN * H_OUT * 2);   // 131 KB
    int*            deg  = (int*)alloc((size_t)N_NODES * 4);                   // 400 KB
    int*            csrp = (int*)alloc((size_t)N_NODES * MAXDEG * 4);          // 12.8 MB
    (void)ws_size; (void)in_sizes; (void)n_in; (void)out_size;

    hipMemsetAsync(deg, 0, (size_t)N_NODES * 4, stream);

    k1 <<<NEB + 256, 256, 0, stream>>>(ei, deg, csrp, W, Wt);
    k2 <<<25000, 256, 0, stream>>>(deg, x, xs);
    k5 <<<12500, 256, 0, stream>>>(xs, csrp, deg, xa);   // 8 nodes/block
    k6 <<<1564, 256, 0, stream>>>((const unsigned short*)xa,
                                  (const unsigned short*)Wt, bias, pw, out);
}

// Round 13
// 126.080 us; speedup vs baseline: 1.2613x; 1.2613x over previous
//
#include <hip/hip_runtime.h>

// GCN forward: out = PReLU( D^-1/2 (A+I) D^-1/2 (x@W) + b )
// Aggregation commutes with the linear map:
//   xs[i,:] = bf16( dinv[i] * x[i,:] ),  dinv[i] = rsqrt(deg[i]+1)
//   xa[i,:] = bf16( dinv[i] * ( xs[i,:] + sum_{s->i} xs[s,:] ) )
//   out     = PReLU( xa @ W + b )
// R13 = R11 (k1/k2/k5 identical; R12's bundle reverted) + A-resident k6:
// one block per 128-row m-tile stages xa ONCE and loops 4 Wt n-chunks
// (xa traffic 102 MB -> 25.6 MB; Wt re-reads are L2-hot, 131 KB total).

typedef __attribute__((ext_vector_type(8))) short bf16x8_t;
typedef __attribute__((ext_vector_type(4))) float f32x4;

#define N_NODES 100000
#define N_EDGES 500000
#define K_IN    128
#define H_OUT   512
#define MAXDEG  32
#define NEB     1954     // ceil(N_EDGES/256)
#define NMT     782      // ceil(N_NODES/128)

static __device__ __forceinline__ unsigned short f2b(float f) {
    unsigned u = __float_as_uint(f);
    u = (u + 0x7FFFu + ((u >> 16) & 1u)) >> 16;   // RNE
    return (unsigned short)u;
}
static __device__ __forceinline__ float b2lo(unsigned v) {
    return __uint_as_float(v << 16);
}
static __device__ __forceinline__ float b2hi(unsigned v) {
    return __uint_as_float(v & 0xFFFF0000u);
}

// K1: deg histogram + INLINE padded-CSR fill (atomic old value = slot) | prepW
__global__ __launch_bounds__(256) void k1(const int* __restrict__ ei,
                                          int* __restrict__ deg,
                                          int* __restrict__ csrp,
                                          const float* __restrict__ W,
                                          unsigned short* __restrict__ Wt) {
    int b = blockIdx.x;
    if (b < NEB) {
        int e = b * 256 + threadIdx.x;
        if (e < N_EDGES) {
            int s = ei[e];
            int d = ei[N_EDGES + e];
            int r = atomicAdd(&deg[d], 1);
            csrp[d * MAXDEG + r] = s;
        }
    } else {
        int i = (b - NEB) * 256 + threadIdx.x;   // i = n*128+k
        int n = i >> 7, k = i & 127;
        Wt[i] = f2b(W[k * H_OUT + n]);
    }
}

// K2: xs[i] = bf16( rsqrt(deg+1) * x[i] ) — pure streaming.
__global__ __launch_bounds__(256) void k2(const int* __restrict__ deg,
                                          const float* __restrict__ x,
                                          unsigned* __restrict__ xs) {
    int i = blockIdx.x * 256 + threadIdx.x;      // 0 .. 6.4M-1
    int row = i >> 6;
    float d = rsqrtf((float)(deg[row] + 1));     // broadcast across wave
    const float2* x2 = (const float2*)x;
    float2 xv = x2[i];
    xs[i] = ((unsigned)f2b(d * xv.y) << 16) | f2b(d * xv.x);
}

// K5 (R11): 1 wave/node; adjacency as int4 pairs; unconditional clamped
// gathers, value-masked accumulate; plain xa store (keeps xa L2-resident).
__global__ __launch_bounds__(256) void k5(const unsigned* __restrict__ xs,
                                          const int* __restrict__ csrp,
                                          const int* __restrict__ deg,
                                          unsigned* __restrict__ xa) {
    int wave = threadIdx.x >> 6, lane = threadIdx.x & 63;
    int node = blockIdx.x * 4 + wave;
    if (node >= N_NODES) return;

    unsigned sv = xs[(size_t)node * 64 + lane];
    int cnt = __builtin_amdgcn_readfirstlane(deg[node]);
    float a0 = b2lo(sv), a1 = b2hi(sv);

    const int4* cp = (const int4*)(csrp + node * MAXDEG);
    for (int j = 0; j < cnt; j += 8) {
        int4 ca = cp[(j >> 2)];
        int4 cb = cp[(j >> 2) + 1];
        unsigned idx[8] = {(unsigned)ca.x, (unsigned)ca.y, (unsigned)ca.z, (unsigned)ca.w,
                           (unsigned)cb.x, (unsigned)cb.y, (unsigned)cb.z, (unsigned)cb.w};
        unsigned v[8];
        #pragma unroll
        for (int t = 0; t < 8; ++t) {
            unsigned id = idx[t] < N_NODES ? idx[t] : 0u;   // clamp poison
            v[t] = xs[(size_t)id * 64 + lane];
        }
        int rem = cnt - j;   // wave-uniform
        #pragma unroll
        for (int t = 0; t < 8; ++t) {
            unsigned val = (t < rem) ? v[t] : 0u;
            a0 += b2lo(val);
            a1 += b2hi(val);
        }
    }
    float di = rsqrtf((float)(cnt + 1));
    xa[(size_t)node * 64 + lane] = ((unsigned)f2b(di * a1) << 16) | f2b(di * a0);
}

// K6: A-resident GEMM. One block per 128-row m-tile (8 waves, 512 thr):
// stage swizzled xa tile once into sA; loop 4 n-chunks staging 128x128 Wt
// into sB; 2m x 4n wave grid, 4x2 frags; epilogue per chunk through ep
// (aliases sB) in 2 half-row phases, nontemporal f32x4 stores.
// Bijective XCD swizzle for NWG=782 (q=97, r=6).
__global__ __launch_bounds__(512) void k6(const unsigned short* __restrict__ xa,
                                          const unsigned short* __restrict__ Wt,
                                          const float* __restrict__ bias,
                                          const float* __restrict__ pw,
                                          float* __restrict__ out) {
    __shared__ char smem[65536];
    uint4* sA = (uint4*)smem;              // 32 KB: A tile, persists
    uint4* sB = (uint4*)(smem + 32768);    // 32 KB: Wt chunk
    float* ep = (float*)(smem + 32768);    // epilogue alias over sB: 64x128 f32

    int orig = blockIdx.x;
    int xcd = orig & 7, loc = orig >> 3;
    int wgid = (xcd < 6 ? xcd * 98 : 588 + (xcd - 6) * 97) + loc;
    const int m0 = wgid * 128;
    const int tid = threadIdx.x;
    const int wave = tid >> 6, lane = tid & 63;

    const uint4* A4 = (const uint4*)xa;
    const uint4* B4 = (const uint4*)Wt;

    // stage A once (2048 uint4 / 512 threads = 4 each)
    #pragma unroll
    for (int r = 0; r < 4; ++r) {
        int i = tid + r * 512;
        int row = i >> 4, c = i & 15;
        int grow = m0 + row;
        uint4 o = (grow < N_NODES) ? A4[(size_t)grow * 16 + c]
                                   : make_uint4(0u, 0u, 0u, 0u);
        sA[row * 16 + (c ^ (row & 7))] = o;
    }

    const int wr = wave >> 2, wc = wave & 3;     // 2m x 4n wave grid
    const int l16 = lane & 15, lq = lane >> 4;

    for (int nc = 0; nc < 4; ++nc) {
        // stage B chunk (rows nc*128 .. +127 of Wt[512][128])
        #pragma unroll
        for (int r = 0; r < 4; ++r) {
            int i = tid + r * 512;
            int row = i >> 4, c = i & 15;
            sB[row * 16 + (c ^ (row & 7))] = B4[(size_t)(nc * 128 + row) * 16 + c];
        }
        __syncthreads();   // A (first iter) + B visible

        f32x4 acc[4][2];
        #pragma unroll
        for (int m = 0; m < 4; ++m)
            #pragma unroll
            for (int n = 0; n < 2; ++n)
                acc[m][n] = (f32x4){0.f, 0.f, 0.f, 0.f};

        #pragma unroll
        for (int kk = 0; kk < 4; ++kk) {
            bf16x8_t av[4], bv[2];
            #pragma unroll
            for (int m = 0; m < 4; ++m) {
                int row = wr * 64 + m * 16 + l16;
                av[m] = __builtin_bit_cast(bf16x8_t, sA[row * 16 + ((kk * 4 + lq) ^ (row & 7))]);
            }
            #pragma unroll
            for (int n = 0; n < 2; ++n) {
                int row = wc * 32 + n * 16 + l16;
                bv[n] = __builtin_bit_cast(bf16x8_t, sB[row * 16 + ((kk * 4 + lq) ^ (row & 7))]);
            }
            #pragma unroll
            for (int m = 0; m < 4; ++m)
                #pragma unroll
                for (int n = 0; n < 2; ++n)
                    acc[m][n] = __builtin_amdgcn_mfma_f32_16x16x32_bf16(av[m], bv[n], acc[m][n], 0, 0, 0);
        }
        __syncthreads();   // sB reads done before ep overwrites it

        float bn[2], pn[2];
        #pragma unroll
        for (int n = 0; n < 2; ++n) {
            int gn = nc * 128 + wc * 32 + n * 16 + l16;
            bn[n] = bias[gn];
            pn[n] = pw[gn];
        }

        // epilogue: 2 half-row phases (wr==h writes rows h*64..h*64+63)
        #pragma unroll
        for (int h = 0; h < 2; ++h) {
            if (wr == h) {
                #pragma unroll
                for (int m = 0; m < 4; ++m)
                    #pragma unroll
                    for (int r = 0; r < 4; ++r) {
                        int row = m * 16 + lq * 4 + r;   // 0..63 within half
                        #pragma unroll
                        for (int n = 0; n < 2; ++n) {
                            float t = acc[m][n][r] + bn[n];
                            float v = t >= 0.f ? t : pn[n] * t;
                            ep[row * 128 + wc * 32 + n * 16 + l16] = v;
                        }
                    }
            }
            __syncthreads();
            // read back: 32 threads/row (128 f32 = 32 f32x4), 16 rows/iter
            #pragma unroll
            for (int it = 0; it < 4; ++it) {
                int row = it * 16 + (tid >> 5);
                int gm = m0 + h * 64 + row;
                if (gm < N_NODES) {
                    int c4 = tid & 31;
                    f32x4 v = *(const f32x4*)&ep[row * 128 + c4 * 4];
                    __builtin_nontemporal_store(v, (f32x4*)&out[(size_t)gm * H_OUT + nc * 128 + c4 * 4]);
                }
            }
            __syncthreads();   // ep reads done before next phase / next chunk
        }
    }
}

extern "C" void kernel_launch(void* const* d_in, const int* in_sizes, int n_in,
                              void* d_out, int out_size, void* d_ws, size_t ws_size,
                              hipStream_t stream) {
    const float* x    = (const float*)d_in[0];
    const int*   ei   = (const int*)d_in[1];
    const float* W    = (const float*)d_in[2];
    const float* bias = (const float*)d_in[3];
    const float* pw   = (const float*)d_in[4];
    float* out = (float*)d_out;

    char* ws = (char*)d_ws;
    size_t off = 0;
    auto alloc = [&](size_t bytes) -> void* {
        void* p = ws + off;
        off += (bytes + 255) & ~(size_t)255;
        return p;
    };
    unsigned*       xs   = (unsigned*)alloc((size_t)N_NODES * K_IN * 2);       // 25.6 MB
    unsigned*       xa   = (unsigned*)alloc((size_t)N_NODES * K_IN * 2);       // 25.6 MB
    unsigned short* Wt   = (unsigned short*)alloc((size_t)K_IN * H_OUT * 2);   // 131 KB
    int*            deg  = (int*)alloc((size_t)N_NODES * 4);                   // 400 KB
    int*            csrp = (int*)alloc((size_t)N_NODES * MAXDEG * 4);          // 12.8 MB
    (void)ws_size; (void)in_sizes; (void)n_in; (void)out_size;

    hipMemsetAsync(deg, 0, (size_t)N_NODES * 4, stream);

    k1 <<<NEB + 256, 256, 0, stream>>>(ei, deg, csrp, W, Wt);
    k2 <<<25000, 256, 0, stream>>>(deg, x, xs);
    k5 <<<(N_NODES + 3) / 4, 256, 0, stream>>>(xs, csrp, deg, xa);
    k6 <<<NMT, 512, 0, stream>>>((const unsigned short*)xa,
                                 (const unsigned short*)Wt, bias, pw, out);
}